// Round 1
// baseline (101.339 us; speedup 1.0000x reference)
//
#include <hip/hip_runtime.h>
#include <math.h>

#define EPS_F 0.0001f

__device__ __forceinline__ float sigmoidf_(float x) {
    return 1.0f / (1.0f + __expf(-x));
}

__device__ __forceinline__ float piecewise_(float nlb, float nub, float inv, float x) {
    // where(x <= lb, 1, where(x > ub, 0, (ub-x)/(ub-lb+EPS)))
    float ramp = (nub - x) * inv;
    return x <= nlb ? 1.0f : (x > nub ? 0.0f : ramp);
}

// 4 rows per thread: 12 ints = 3 x int4 cached loads, 4 floats = 1 x float4 store.
// NOTE: do NOT use nontemporal hints here — the harness's d_in restore pass
// leaves obs_idx warm in the 256 MiB L3; NT bypass regressed 102.5 -> 118.3 us (R3).
extern "C" __global__ __launch_bounds__(256) void perf_model_kernel(
    const float* __restrict__ bc,        // bin_centers
    const int*   __restrict__ idx,       // obs_idx, row-major (n,3)
    const float* __restrict__ lb1p, const float* __restrict__ ub1p,
    const float* __restrict__ lb2p, const float* __restrict__ ub2p,
    const float* __restrict__ respp,
    float* __restrict__ out,
    int n,        // number of rows
    int n_bins)
{
    extern __shared__ float sbc[];
    for (int i = threadIdx.x; i < n_bins; i += blockDim.x)
        sbc[i] = bc[i];
    __syncthreads();

    const float lb1 = lb1p[0], ub1 = ub1p[0];
    const float lb2 = lb2p[0], ub2 = ub2p[0];
    const float nlb1 = sigmoidf_(fminf(lb1, ub1));
    const float nub1 = sigmoidf_(fmaxf(lb1, ub1));
    const float nlb2 = sigmoidf_(fminf(lb2, ub2));
    const float nub2 = sigmoidf_(fmaxf(lb2, ub2));
    const float r    = sigmoidf_(respp[0]);
    const float inv1 = 1.0f / (nub1 - nlb1 + EPS_F);
    const float inv2 = 1.0f / (nub2 - nlb2 + EPS_F);

    const int t = blockIdx.x * blockDim.x + threadIdx.x;
    const int row0 = t * 4;
    if (row0 >= n) return;

    if (row0 + 3 < n) {
        // 4 rows = 12 ints = 3 x int4 fully-coalesced loads
        const int4* idx4 = (const int4*)(idx + (size_t)row0 * 3);
        int4 a = idx4[0];
        int4 b = idx4[1];
        int4 c = idx4[2];
        int i0[4] = {a.x, a.w, b.z, c.y};
        int i1[4] = {a.y, b.x, b.w, c.z};
        float4 o;
        float* op = (float*)&o;
        #pragma unroll
        for (int k = 0; k < 4; ++k) {
            float x1 = sbc[i0[k]];
            float x2 = sbc[i1[k]];
            op[k] = piecewise_(nlb1, nub1, inv1, x1) *
                    piecewise_(nlb2, nub2, inv2, x2) * r;
        }
        *(float4*)(out + row0) = o;
    } else {
        // tail: scalar per-row
        for (int rrow = row0; rrow < n; ++rrow) {
            float x1 = sbc[idx[(size_t)rrow * 3 + 0]];
            float x2 = sbc[idx[(size_t)rrow * 3 + 1]];
            out[rrow] = piecewise_(nlb1, nub1, inv1, x1) *
                        piecewise_(nlb2, nub2, inv2, x2) * r;
        }
    }
}

extern "C" void kernel_launch(void* const* d_in, const int* in_sizes, int n_in,
                              void* d_out, int out_size, void* d_ws, size_t ws_size,
                              hipStream_t stream) {
    const float* bc   = (const float*)d_in[0];
    const int*   idx  = (const int*)d_in[1];
    const float* lb1  = (const float*)d_in[2];
    const float* ub1  = (const float*)d_in[3];
    const float* lb2  = (const float*)d_in[4];
    const float* ub2  = (const float*)d_in[5];
    const float* resp = (const float*)d_in[6];
    float* out = (float*)d_out;

    const int n_bins = in_sizes[0];
    const int n      = in_sizes[1] / 3;   // rows of obs_idx

    const int rows_per_thread = 4;
    const int nthreads = (n + rows_per_thread - 1) / rows_per_thread;
    const int block = 256;
    const int grid  = (nthreads + block - 1) / block;
    const size_t smem = (size_t)n_bins * sizeof(float);

    perf_model_kernel<<<grid, block, smem, stream>>>(
        bc, idx, lb1, ub1, lb2, ub2, resp, out, n, n_bins);
}

// Round 2
// 101.254 us; speedup vs baseline: 1.0008x; 1.0008x over previous
//
#include <hip/hip_runtime.h>
#include <math.h>

#define EPS_F 0.0001f

__device__ __forceinline__ float sigmoidf_(float x) {
    return 1.0f / (1.0f + __expf(-x));
}

__device__ __forceinline__ float piecewise_(float nlb, float nub, float inv, float x) {
    // where(x <= lb, 1, where(x > ub, 0, (ub-x)/(ub-lb+EPS)))
    float ramp = (nub - x) * inv;
    return x <= nlb ? 1.0f : (x > nub ? 0.0f : ramp);
}

// 8 rows per thread: 24 ints = 6 x int4 coalesced loads, 8 floats = 2 x float4 stores.
// Piecewise values precomputed per-bin into LDS tables (sp1/sp2, 8 KB) so the
// per-row chain is just 2 LDS gathers + 2 muls — identical op order to the
// reference ((p1*p2)*r with ramp=(nub-x)*inv), so absmax stays 0.
// NOTE: do NOT use nontemporal hints — R3 measured 102.5 -> 118.3 us regression.
extern "C" __global__ __launch_bounds__(256) void perf_model_kernel(
    const float* __restrict__ bc,        // bin_centers
    const int*   __restrict__ idx,       // obs_idx, row-major (n,3)
    const float* __restrict__ lb1p, const float* __restrict__ ub1p,
    const float* __restrict__ lb2p, const float* __restrict__ ub2p,
    const float* __restrict__ respp,
    float* __restrict__ out,
    int n,        // number of rows
    int n_bins)
{
    extern __shared__ float smem[];
    float* sp1 = smem;              // n_bins floats
    float* sp2 = smem + n_bins;     // n_bins floats

    const float lb1 = lb1p[0], ub1 = ub1p[0];
    const float lb2 = lb2p[0], ub2 = ub2p[0];
    const float nlb1 = sigmoidf_(fminf(lb1, ub1));
    const float nub1 = sigmoidf_(fmaxf(lb1, ub1));
    const float nlb2 = sigmoidf_(fminf(lb2, ub2));
    const float nub2 = sigmoidf_(fmaxf(lb2, ub2));
    const float r    = sigmoidf_(respp[0]);
    const float inv1 = 1.0f / (nub1 - nlb1 + EPS_F);
    const float inv2 = 1.0f / (nub2 - nlb2 + EPS_F);

    for (int i = threadIdx.x; i < n_bins; i += blockDim.x) {
        float x = bc[i];
        sp1[i] = piecewise_(nlb1, nub1, inv1, x);
        sp2[i] = piecewise_(nlb2, nub2, inv2, x);
    }
    __syncthreads();

    const int t = blockIdx.x * blockDim.x + threadIdx.x;
    const int row0 = t * 8;
    if (row0 >= n) return;

    if (row0 + 7 < n) {
        // 8 rows = 24 ints = 6 x int4 fully-coalesced loads (16B-aligned: t*96)
        const int4* idx4 = (const int4*)(idx + (size_t)row0 * 3);
        int4 a = idx4[0];
        int4 b = idx4[1];
        int4 c = idx4[2];
        int4 d = idx4[3];
        int4 e = idx4[4];
        int4 f = idx4[5];
        int i0[8] = {a.x, a.w, b.z, c.y, d.x, d.w, e.z, f.y};
        int i1[8] = {a.y, b.x, b.w, c.z, d.y, e.x, e.w, f.z};
        float o[8];
        #pragma unroll
        for (int k = 0; k < 8; ++k) {
            o[k] = sp1[i0[k]] * sp2[i1[k]] * r;
        }
        *(float4*)(out + row0)     = make_float4(o[0], o[1], o[2], o[3]);
        *(float4*)(out + row0 + 4) = make_float4(o[4], o[5], o[6], o[7]);
    } else {
        // tail: scalar per-row
        for (int rrow = row0; rrow < n; ++rrow) {
            float p1 = sp1[idx[(size_t)rrow * 3 + 0]];
            float p2 = sp2[idx[(size_t)rrow * 3 + 1]];
            out[rrow] = p1 * p2 * r;
        }
    }
}

extern "C" void kernel_launch(void* const* d_in, const int* in_sizes, int n_in,
                              void* d_out, int out_size, void* d_ws, size_t ws_size,
                              hipStream_t stream) {
    const float* bc   = (const float*)d_in[0];
    const int*   idx  = (const int*)d_in[1];
    const float* lb1  = (const float*)d_in[2];
    const float* ub1  = (const float*)d_in[3];
    const float* lb2  = (const float*)d_in[4];
    const float* ub2  = (const float*)d_in[5];
    const float* resp = (const float*)d_in[6];
    float* out = (float*)d_out;

    const int n_bins = in_sizes[0];
    const int n      = in_sizes[1] / 3;   // rows of obs_idx

    const int rows_per_thread = 8;
    const int nthreads = (n + rows_per_thread - 1) / rows_per_thread;
    const int block = 256;
    const int grid  = (nthreads + block - 1) / block;
    const size_t smem = (size_t)(2 * n_bins) * sizeof(float);

    perf_model_kernel<<<grid, block, smem, stream>>>(
        bc, idx, lb1, ub1, lb2, ub2, resp, out, n, n_bins);
}

// Round 3
// 98.476 us; speedup vs baseline: 1.0291x; 1.0282x over previous
//
#include <hip/hip_runtime.h>
#include <math.h>

#define EPS_F 0.0001f

__device__ __forceinline__ float sigmoidf_(float x) {
    return 1.0f / (1.0f + __expf(-x));
}

__device__ __forceinline__ float piecewise_(float nlb, float nub, float inv, float x) {
    // where(x <= lb, 1, where(x > ub, 0, (ub-x)/(ub-lb+EPS)))
    float ramp = (nub - x) * inv;
    return x <= nlb ? 1.0f : (x > nub ? 0.0f : ramp);
}

// 8 rows per thread, block=512 (grid = exactly 1024 blocks = 4 blocks/CU = full
// single-generation residency). Key change vs R2: the 6 int4 idx loads are
// issued BEFORE the LDS table build + __syncthreads, so the idx memory-latency
// round trip overlaps the prologue instead of following it. With only one
// generation of waves there is no wave turnover to hide that latency otherwise.
// Piecewise values precomputed per-bin into LDS (sp1/sp2, 8 KB); per-row chain
// is 2 LDS gathers + 2 muls, same op order as reference -> absmax 0.
// NOTE: do NOT use nontemporal hints — R3 (prev session) measured 102.5 -> 118.3 us.
extern "C" __global__ __launch_bounds__(512) void perf_model_kernel(
    const float* __restrict__ bc,        // bin_centers
    const int*   __restrict__ idx,       // obs_idx, row-major (n,3)
    const float* __restrict__ lb1p, const float* __restrict__ ub1p,
    const float* __restrict__ lb2p, const float* __restrict__ ub2p,
    const float* __restrict__ respp,
    float* __restrict__ out,
    int n,        // number of rows
    int n_bins)
{
    extern __shared__ float smem[];
    float* sp1 = smem;              // n_bins floats
    float* sp2 = smem + n_bins;     // n_bins floats

    const int t = blockIdx.x * blockDim.x + threadIdx.x;
    const int row0 = t * 8;
    const bool full = (row0 + 7 < n);

    // ---- prefetch idx FIRST: 6 x int4 issued before any LDS/sync work ----
    int4 a, b, c, d, e, f;
    if (full) {
        const int4* idx4 = (const int4*)(idx + (size_t)row0 * 3);
        a = idx4[0];
        b = idx4[1];
        c = idx4[2];
        d = idx4[3];
        e = idx4[4];
        f = idx4[5];
    }

    // ---- scalar params + LDS table build (overlaps idx load latency) ----
    const float lb1 = lb1p[0], ub1 = ub1p[0];
    const float lb2 = lb2p[0], ub2 = ub2p[0];
    const float nlb1 = sigmoidf_(fminf(lb1, ub1));
    const float nub1 = sigmoidf_(fmaxf(lb1, ub1));
    const float nlb2 = sigmoidf_(fminf(lb2, ub2));
    const float nub2 = sigmoidf_(fmaxf(lb2, ub2));
    const float r    = sigmoidf_(respp[0]);
    const float inv1 = 1.0f / (nub1 - nlb1 + EPS_F);
    const float inv2 = 1.0f / (nub2 - nlb2 + EPS_F);

    for (int i = threadIdx.x; i < n_bins; i += blockDim.x) {
        float x = bc[i];
        sp1[i] = piecewise_(nlb1, nub1, inv1, x);
        sp2[i] = piecewise_(nlb2, nub2, inv2, x);
    }
    __syncthreads();

    if (row0 >= n) return;

    if (full) {
        int i0[8] = {a.x, a.w, b.z, c.y, d.x, d.w, e.z, f.y};
        int i1[8] = {a.y, b.x, b.w, c.z, d.y, e.x, e.w, f.z};
        float o[8];
        #pragma unroll
        for (int k = 0; k < 8; ++k) {
            o[k] = sp1[i0[k]] * sp2[i1[k]] * r;
        }
        *(float4*)(out + row0)     = make_float4(o[0], o[1], o[2], o[3]);
        *(float4*)(out + row0 + 4) = make_float4(o[4], o[5], o[6], o[7]);
    } else {
        // tail: scalar per-row
        for (int rrow = row0; rrow < n; ++rrow) {
            float p1 = sp1[idx[(size_t)rrow * 3 + 0]];
            float p2 = sp2[idx[(size_t)rrow * 3 + 1]];
            out[rrow] = p1 * p2 * r;
        }
    }
}

extern "C" void kernel_launch(void* const* d_in, const int* in_sizes, int n_in,
                              void* d_out, int out_size, void* d_ws, size_t ws_size,
                              hipStream_t stream) {
    const float* bc   = (const float*)d_in[0];
    const int*   idx  = (const int*)d_in[1];
    const float* lb1  = (const float*)d_in[2];
    const float* ub1  = (const float*)d_in[3];
    const float* lb2  = (const float*)d_in[4];
    const float* ub2  = (const float*)d_in[5];
    const float* resp = (const float*)d_in[6];
    float* out = (float*)d_out;

    const int n_bins = in_sizes[0];
    const int n      = in_sizes[1] / 3;   // rows of obs_idx

    const int rows_per_thread = 8;
    const int nthreads = (n + rows_per_thread - 1) / rows_per_thread;
    const int block = 512;
    const int grid  = (nthreads + block - 1) / block;
    const size_t smem = (size_t)(2 * n_bins) * sizeof(float);

    perf_model_kernel<<<grid, block, smem, stream>>>(
        bc, idx, lb1, ub1, lb2, ub2, resp, out, n, n_bins);
}